// Round 6
// baseline (81.367 us; speedup 1.0000x reference)
//
#include <hip/hip_runtime.h>

#define MDIM 4096
#define NDIM 4096
#define NCOEF 768
#define ALPHA 16.0f

typedef __attribute__((ext_vector_type(8))) short bf16x8;
typedef __attribute__((ext_vector_type(4))) float f32x4;

__device__ __forceinline__ unsigned short f2bf(float x) {
    unsigned u = __float_as_uint(x);
    u += 0x7FFFu + ((u >> 16) & 1u);
    return (unsigned short)(u >> 16);
}

// ---- kernel 0: per-coefficient metadata (r, c, scales, dedup) ----
// 12 blocks x 64 threads (one wave each): block b owns p = b*64 + lane.
__global__ __launch_bounds__(64) void meta_kernel(
    const int* __restrict__ fidx, const float* __restrict__ dw,
    int* __restrict__ r_m, int* __restrict__ c_m,
    float* __restrict__ su_m, float* __restrict__ sv_m)
{
    __shared__ int idx_s[NCOEF];
    const int t = threadIdx.x;
    #pragma unroll
    for (int j = 0; j < 12; ++j) idx_s[t + j * 64] = fidx[t + j * 64];
    __syncthreads();
    const int p = blockIdx.x * 64 + t;
    const int idx = idx_s[p];
    // .at[].set semantics: last write wins -> kill earlier duplicates.
    int keep = 1;
    #pragma unroll 16
    for (int q = 0; q < NCOEF; ++q)
        keep &= (q <= p) | (idx_s[q] != idx);
    const int r = idx >> 12;          // / 4096
    const int c = idx & (NDIM - 1);   // % 4096
    const float s0 = 0.015625f;              // sqrt(1/4096)
    const float s1 = 0.022097086912079612f;  // sqrt(2/4096)
    r_m[p] = r;
    c_m[p] = c;
    su_m[p] = (r == 0) ? s0 : s1;
    sv_m[p] = (float)keep * ALPHA * dw[p] * ((c == 0) ? s0 : s1);
}

// ---- kernel 1: materialize U,V in PANEL layout ----
// U_p[((panel*96 + kc)*128 + row)*8 + pi]; i = panel*128+row, p = kc*8+pi.
// One block per (panel,kc): 2 KB contiguous per array. Integer-exact reduction.
__global__ __launch_bounds__(256) void fill_uv(
    const int* __restrict__ r_m, const int* __restrict__ c_m,
    const float* __restrict__ su_m, const float* __restrict__ sv_m,
    unsigned short* __restrict__ U, unsigned short* __restrict__ V)
{
    const int b = blockIdx.x;            // b = panel*96 + kc, 0..3071
    const int panel = b / 96;
    const int kc = b - panel * 96;
    const int t = threadIdx.x;
    const int row = (panel << 7) + (t >> 1);
    const int p0 = (kc << 3) + ((t & 1) << 2);
    const unsigned tt = 2u * (unsigned)row + 1u;
    const float w = 3.14159265358979323846f / 8192.0f;
    unsigned short uo[4], vo[4];
    #pragma unroll
    for (int j = 0; j < 4; ++j) {
        const int p = p0 + j;
        const unsigned nu = (tt * (unsigned)r_m[p]) & 16383u;
        const unsigned nv = (tt * (unsigned)c_m[p]) & 16383u;
        uo[j] = f2bf(su_m[p] * cosf((float)nu * w));
        vo[j] = f2bf(sv_m[p] * cosf((float)nv * w));
    }
    const size_t o = (size_t)b * 1024 + (size_t)t * 4;
    *(ushort4*)(U + o) = *(const ushort4*)uo;
    *(ushort4*)(V + o) = *(const ushort4*)vo;
}

// ---- kernel 2: out = W + U @ V^T  (M=N=4096, K=768) ----
// NO LDS, NO barriers. Panel layout == MFMA fragment layout, so each lane
// loads its A/B fragments DIRECTLY from global (16B, fully coalesced per
// wave; U/V are L2-resident: 12 MB total, ~4.5 MB per XCD with rectangle
// swizzle). Register double-buffer, fully unrolled K-loop (static indices).
// MFMA operands swapped (mfma(b,a)): lane's 4 acc regs = 4 consecutive out
// columns -> float4 epilogue.
__global__ __launch_bounds__(256, 3) void gemm_kernel(
    const float* __restrict__ W,
    const unsigned short* __restrict__ U,
    const unsigned short* __restrict__ V,
    float* __restrict__ out)
{
    const int tid = threadIdx.x;
    const int lane = tid & 63;
    const int wave = tid >> 6;

    // XCD rectangle swizzle: 8 XCDs, each gets an 8(by) x 16(bx) rectangle:
    // U panels 8*192KB = 1.5MB + V panels 16*192KB = 3MB per XCD L2.
    const int bid = blockIdx.x;
    const int xcd = bid & 7;
    const int local = bid >> 3;               // 0..127
    const int by = ((xcd >> 1) << 3) + (local >> 4);
    const int bx = ((xcd & 1) << 4) + (local & 15);
    const int brow = by * 128;
    const int bcol = bx * 128;
    const int wr = wave >> 1;
    const int wc = wave & 1;

    // fragment base: lane l, frag f -> chunk = fks*128 + w*64 + f*16 + fr
    const int fr = lane & 15;
    const int fks = lane >> 4;
    const unsigned short* aP = U + (size_t)by * 96 * 1024
                                 + (size_t)((fks * 128 + wr * 64 + fr) << 3);
    const unsigned short* bP = V + (size_t)bx * 96 * 1024
                                 + (size_t)((fks * 128 + wc * 64 + fr) << 3);

    f32x4 acc[4][4] = {};
    bf16x8 aR[2][4], bR[2][4];   // static-indexed under full unroll

    #pragma unroll
    for (int f = 0; f < 4; ++f) {
        aR[0][f] = *(const bf16x8*)(aP + (f << 7));
        bR[0][f] = *(const bf16x8*)(bP + (f << 7));
    }
    #pragma unroll
    for (int i = 0; i < 24; ++i) {
        const int cur = i & 1, nxt = (i & 1) ^ 1;
        if (i < 23) {
            const unsigned short* aN = aP + (size_t)(i + 1) * 4096;
            const unsigned short* bN = bP + (size_t)(i + 1) * 4096;
            #pragma unroll
            for (int f = 0; f < 4; ++f) {
                aR[nxt][f] = *(const bf16x8*)(aN + (f << 7));
                bR[nxt][f] = *(const bf16x8*)(bN + (f << 7));
            }
        }
        #pragma unroll
        for (int fm = 0; fm < 4; ++fm)
            #pragma unroll
            for (int fn = 0; fn < 4; ++fn)
                acc[fm][fn] = __builtin_amdgcn_mfma_f32_16x16x32_bf16(
                    bR[cur][fn], aR[cur][fm], acc[fm][fn], 0, 0, 0);
    }

    // epilogue: out = W + acc (alpha folded into V). Swapped-operand C/D
    // layout: lane holds row = lane&15 (fixed), cols = (lane>>4)*4 .. +3.
    const int erow = brow + wr * 64 + fr;
    const int ecol = bcol + wc * 64 + (fks << 2);
    #pragma unroll
    for (int fm = 0; fm < 4; ++fm) {
        #pragma unroll
        for (int fn = 0; fn < 4; ++fn) {
            const size_t o = (size_t)(erow + fm * 16) * NDIM + (ecol + fn * 16);
            const float4 w4 = *(const float4*)(W + o);
            float4 r4;
            r4.x = w4.x + acc[fm][fn][0];
            r4.y = w4.y + acc[fm][fn][1];
            r4.z = w4.z + acc[fm][fn][2];
            r4.w = w4.w + acc[fm][fn][3];
            *(float4*)(out + o) = r4;
        }
    }
}

extern "C" void kernel_launch(void* const* d_in, const int* in_sizes, int n_in,
                              void* d_out, int out_size, void* d_ws, size_t ws_size,
                              hipStream_t stream) {
    const float* weight = (const float*)d_in[0];
    const float* dw     = (const float*)d_in[1];
    const int*   fidx   = (const int*)d_in[2];
    float* out = (float*)d_out;

    char* ws = (char*)d_ws;
    unsigned short* U = (unsigned short*)ws;                       // 6,291,456 B
    unsigned short* V = (unsigned short*)(ws + 6291456);           // 6,291,456 B
    char* meta = ws + 2 * 6291456;
    int*   r_m  = (int*)(meta);
    int*   c_m  = (int*)(meta + NCOEF * 4);
    float* su_m = (float*)(meta + NCOEF * 8);
    float* sv_m = (float*)(meta + NCOEF * 12);

    meta_kernel<<<12, 64, 0, stream>>>(fidx, dw, r_m, c_m, su_m, sv_m);
    fill_uv<<<32 * 96, 256, 0, stream>>>(r_m, c_m, su_m, sv_m, U, V);
    gemm_kernel<<<1024, 256, 0, stream>>>(weight, U, V, out);
}

// Round 7
// 68.582 us; speedup vs baseline: 1.1864x; 1.1864x over previous
//
#include <hip/hip_runtime.h>

#define MDIM 4096
#define NDIM 4096
#define NCOEF 768
#define ALPHA 16.0f
#define PANEL_U16 (96 * 256 * 8)   // u16 per 256-row panel

typedef __attribute__((ext_vector_type(8))) short bf16x8;
typedef __attribute__((ext_vector_type(4))) float f32x4;

__device__ __forceinline__ unsigned short f2bf(float x) {
    unsigned u = __float_as_uint(x);
    u += 0x7FFFu + ((u >> 16) & 1u);
    return (unsigned short)(u >> 16);
}

__device__ __forceinline__ void glds16(const unsigned short* src, unsigned short* dst) {
    __builtin_amdgcn_global_load_lds(
        (const __attribute__((address_space(1))) void*)src,
        (__attribute__((address_space(3))) void*)dst, 16, 0, 0);
}

// ---- kernel 0: per-coefficient metadata (r, c, scales, dedup) ----
__global__ __launch_bounds__(64) void meta_kernel(
    const int* __restrict__ fidx, const float* __restrict__ dw,
    int* __restrict__ r_m, int* __restrict__ c_m,
    float* __restrict__ su_m, float* __restrict__ sv_m)
{
    __shared__ int idx_s[NCOEF];
    const int t = threadIdx.x;
    #pragma unroll
    for (int j = 0; j < 12; ++j) idx_s[t + j * 64] = fidx[t + j * 64];
    __syncthreads();
    const int p = blockIdx.x * 64 + t;
    const int idx = idx_s[p];
    int keep = 1;                        // last write wins
    #pragma unroll 16
    for (int q = 0; q < NCOEF; ++q)
        keep &= (q <= p) | (idx_s[q] != idx);
    const int r = idx >> 12;
    const int c = idx & (NDIM - 1);
    const float s0 = 0.015625f;              // sqrt(1/4096)
    const float s1 = 0.022097086912079612f;  // sqrt(2/4096)
    r_m[p] = r;
    c_m[p] = c;
    su_m[p] = (r == 0) ? s0 : s1;
    sv_m[p] = (float)keep * ALPHA * dw[p] * ((c == 0) ? s0 : s1);
}

// ---- kernel 1: materialize U,V in 256-row PANEL layout ----
// U[((panel*96 + kc)*256 + row)*8 + pi]; i = panel*256+row, p = kc*8+pi.
// Each BK=64 K-tile (8 kc) of a panel is a contiguous 32 KB slab whose linear
// order equals the k-outer LDS layout. Block = (panel,kc,half): 1 KB x2 writes.
__global__ __launch_bounds__(256) void fill_uv(
    const int* __restrict__ r_m, const int* __restrict__ c_m,
    const float* __restrict__ su_m, const float* __restrict__ sv_m,
    unsigned short* __restrict__ U, unsigned short* __restrict__ V)
{
    const int b = blockIdx.x;            // (panel*96 + kc)*2 + half
    const int half = b & 1;
    const int pk = b >> 1;               // panel*96 + kc
    const int panel = pk / 96;
    const int kc = pk - panel * 96;
    const int t = threadIdx.x;
    const int rl = (half << 7) + (t >> 1);        // rowLocal 0..255
    const int row = (panel << 8) + rl;            // global i
    const int p0 = (kc << 3) + ((t & 1) << 2);
    const unsigned tt = 2u * (unsigned)row + 1u;
    const float w = 3.14159265358979323846f / 8192.0f;
    unsigned short uo[4], vo[4];
    #pragma unroll
    for (int j = 0; j < 4; ++j) {
        const int p = p0 + j;
        const unsigned nu = (tt * (unsigned)r_m[p]) & 16383u;
        const unsigned nv = (tt * (unsigned)c_m[p]) & 16383u;
        uo[j] = f2bf(su_m[p] * cosf((float)nu * w));
        vo[j] = f2bf(sv_m[p] * cosf((float)nv * w));
    }
    const size_t o = ((size_t)pk * 256 + rl) * 8 + ((t & 1) << 2);
    *(ushort4*)(U + o) = *(const ushort4*)uo;
    *(ushort4*)(V + o) = *(const ushort4*)vo;
}

// ---- kernel 2: out = W + U @ V^T  (M=N=4096, K=768) ----
// 256x256 tile, 8 waves (2x4), BK=64, 12 K-iters. 2-buffer 128 KB LDS,
// counted vmcnt, 2 barriers/iter (R4-proven shape, coarser grain). Each wave:
// 128x64 output = 8x4 frags. Stage: 8 KB/instr, contiguous slabs. W rows 0..31
// prefetched at iter 10 (compiler-managed wait) to hide epilogue HBM latency.
__global__ __launch_bounds__(512, 2) void gemm_kernel(
    const float* __restrict__ W,
    const unsigned short* __restrict__ U,
    const unsigned short* __restrict__ V,
    float* __restrict__ out)
{
    __shared__ unsigned short As[2][16384];
    __shared__ unsigned short Bs[2][16384];

    const int tid = threadIdx.x;         // 0..511
    const int lane = tid & 63;
    const int wave = tid >> 6;           // 0..7

    // XCD rect swizzle: 256 blocks, 8 XCDs, 4(by) x 8(bx) rect per XCD:
    // U 4*384KB + V 8*384KB ~ 4.6 MB per XCD L2.
    const int bid = blockIdx.x;
    const int xcd = bid & 7;
    const int local = bid >> 3;                        // 0..31
    const int by = ((xcd >> 1) << 2) + (local >> 3);   // 0..15
    const int bx = ((xcd & 1) << 3) + (local & 7);     // 0..15
    const int wr = wave >> 2;            // 0..1
    const int wc = wave & 3;             // 0..3
    const int fr = lane & 15;
    const int fks = lane >> 4;

    const unsigned short* uPan = U + (size_t)by * PANEL_U16;
    const unsigned short* vPan = V + (size_t)bx * PANEL_U16;

    f32x4 acc[8][4] = {};

    // epilogue coords (also used for W prefetch)
    const int erow = (by << 8) + wr * 128 + fr;
    const int ecol = (bx << 8) + wc * 64 + (fks << 2);

#define STAGE(j, buf) do {                                                  \
        const unsigned short* uS = uPan + (size_t)(j) * 16384;              \
        const unsigned short* vS = vPan + (size_t)(j) * 16384;              \
        _Pragma("unroll")                                                   \
        for (int q = 0; q < 4; ++q) {                                       \
            glds16(uS + (((q << 9) + tid) << 3),                            \
                   &As[buf][(((q << 9) + (wave << 6)) << 3)]);              \
            glds16(vS + (((q << 9) + tid) << 3),                            \
                   &Bs[buf][(((q << 9) + (wave << 6)) << 3)]);              \
        }                                                                   \
    } while (0)

#define COMPUTE(buf) do {                                                   \
        _Pragma("unroll")                                                   \
        for (int s = 0; s < 2; ++s) {                                       \
            const int kb = ((s << 2) + fks) << 8;   /* kc_local*256 */      \
            bf16x8 a[8], b[4];                                              \
            _Pragma("unroll")                                               \
            for (int fm = 0; fm < 8; ++fm)                                  \
                a[fm] = *(const bf16x8*)&As[buf][(kb + wr * 128 + fm * 16 + fr) << 3]; \
            _Pragma("unroll")                                               \
            for (int fn = 0; fn < 4; ++fn)                                  \
                b[fn] = *(const bf16x8*)&Bs[buf][(kb + wc * 64 + fn * 16 + fr) << 3];  \
            _Pragma("unroll")                                               \
            for (int fm = 0; fm < 8; ++fm)                                  \
                _Pragma("unroll")                                           \
                for (int fn = 0; fn < 4; ++fn)                              \
                    acc[fm][fn] = __builtin_amdgcn_mfma_f32_16x16x32_bf16(  \
                        b[fn], a[fm], acc[fm][fn], 0, 0, 0);                \
        }                                                                   \
    } while (0)

    STAGE(0, 0);
    float4 wpre[8];
    #pragma unroll
    for (int j = 0; j < 12; ++j) {
        if (j < 11) STAGE(j + 1, (j + 1) & 1);
        if (j == 10) {
            // prefetch W for fm=0..1 (compiler inserts the wait at use)
            #pragma unroll
            for (int fm = 0; fm < 2; ++fm)
                #pragma unroll
                for (int fn = 0; fn < 4; ++fn)
                    wpre[fm * 4 + fn] = *(const float4*)(
                        W + (size_t)(erow + fm * 16) * NDIM + (ecol + fn * 16));
        }
        // ensure stage j complete; leave newer (stage j+1 [, W]) in flight
        if (j == 10)      asm volatile("s_waitcnt vmcnt(16)" ::: "memory");
        else              asm volatile("s_waitcnt vmcnt(8)"  ::: "memory");
        __builtin_amdgcn_s_barrier();
        asm volatile("" ::: "memory");
        COMPUTE(j & 1);
        if (j < 11) {
            asm volatile("s_waitcnt lgkmcnt(0)" ::: "memory");
            __builtin_amdgcn_s_barrier();
            asm volatile("" ::: "memory");
        }
    }

    // epilogue: out = W + acc (alpha folded into V). Swapped-operand C/D
    // layout: lane holds row = fr (fixed), cols = fks*4 .. +3 -> float4.
    #pragma unroll
    for (int fm = 0; fm < 2; ++fm) {
        #pragma unroll
        for (int fn = 0; fn < 4; ++fn) {
            const size_t o = (size_t)(erow + fm * 16) * NDIM + (ecol + fn * 16);
            const float4 w4 = wpre[fm * 4 + fn];
            float4 r4;
            r4.x = w4.x + acc[fm][fn][0];
            r4.y = w4.y + acc[fm][fn][1];
            r4.z = w4.z + acc[fm][fn][2];
            r4.w = w4.w + acc[fm][fn][3];
            *(float4*)(out + o) = r4;
        }
    }
    #pragma unroll
    for (int fm = 2; fm < 8; ++fm) {
        #pragma unroll
        for (int fn = 0; fn < 4; ++fn) {
            const size_t o = (size_t)(erow + fm * 16) * NDIM + (ecol + fn * 16);
            const float4 w4 = *(const float4*)(W + o);
            float4 r4;
            r4.x = w4.x + acc[fm][fn][0];
            r4.y = w4.y + acc[fm][fn][1];
            r4.z = w4.z + acc[fm][fn][2];
            r4.w = w4.w + acc[fm][fn][3];
            *(float4*)(out + o) = r4;
        }
    }
#undef STAGE
#undef COMPUTE
}

extern "C" void kernel_launch(void* const* d_in, const int* in_sizes, int n_in,
                              void* d_out, int out_size, void* d_ws, size_t ws_size,
                              hipStream_t stream) {
    const float* weight = (const float*)d_in[0];
    const float* dw     = (const float*)d_in[1];
    const int*   fidx   = (const int*)d_in[2];
    float* out = (float*)d_out;

    char* ws = (char*)d_ws;
    unsigned short* U = (unsigned short*)ws;                       // 6,291,456 B
    unsigned short* V = (unsigned short*)(ws + 6291456);           // 6,291,456 B
    char* meta = ws + 2 * 6291456;
    int*   r_m  = (int*)(meta);
    int*   c_m  = (int*)(meta + NCOEF * 4);
    float* su_m = (float*)(meta + NCOEF * 8);
    float* sv_m = (float*)(meta + NCOEF * 12);

    meta_kernel<<<12, 64, 0, stream>>>(fidx, dw, r_m, c_m, su_m, sv_m);
    fill_uv<<<16 * 96 * 2, 256, 0, stream>>>(r_m, c_m, su_m, sv_m, U, V);
    gemm_kernel<<<256, 512, 0, stream>>>(weight, U, V, out);
}